// Round 1
// baseline (304.155 us; speedup 1.0000x reference)
//
#include <hip/hip_runtime.h>
#include <hip/hip_bf16.h>
#include <hip/hip_fp16.h>

typedef _Float16 f16;
typedef _Float16 f16x8 __attribute__((ext_vector_type(8)));
typedef float f32x16 __attribute__((ext_vector_type(16)));
typedef unsigned int u32;

// Problem sizes (fixed)
#define BB 32
#define SS 2048
#define HH 1024
#define KK 1024

// ws layout (bytes)
#define WS_BP 0                            // packed Wv fp16: 2 MB
#define WS_HQ (2u*1024u*1024u)             // hq fp32: 32*1024*4 = 128 KB
#define WS_LP (WS_HQ + 131072u)            // logits partials: 4*32*2048*4 = 1 MB

__device__ __forceinline__ float tanh_f(float x) {
    // tanh(x) = 1 - 2/(e^{2x}+1); safe at +/-inf of exp
    float e = __expf(2.0f * x);
    return 1.0f - 2.0f * __builtin_amdgcn_rcpf(e + 1.0f);
}

__device__ __forceinline__ void gload_lds16(const void* g, void* l) {
    __builtin_amdgcn_global_load_lds(
        (const __attribute__((address_space(1))) u32*)g,
        (__attribute__((address_space(3))) u32*)l, 16, 0, 0);
}

// ---------------------------------------------------------------------------
// Pack Wv [k][n] fp32 -> fragment-ordered fp16 for mfma_f32_32x32x16_f16 B-operand,
// grouped so each (N-block, K-iter) slice is one contiguous 32 KB chunk:
// BP[ntb(4)][kit(16)][ntl(8)][ksl(4)][lane(64)][j(8)]
// frag layout: B[k][n], lane l: n = l&31, k = ks*16 + (l>>5)*8 + j
__global__ void pack_wv(const float* __restrict__ Wv, f16* __restrict__ BP) {
    int i = blockIdx.x * 256 + threadIdx.x;   // i = k*1024 + n
    int k = i >> 10, n = i & 1023;
    float v = Wv[i];
    int ntb = n >> 8;              // N-block (256 cols)
    int ntl = (n >> 5) & 7;        // local 32-col tile
    int kit = k >> 6;              // K-iter (BK=64)
    int ksl = (k >> 4) & 3;        // local k-step
    int lane = ((k >> 3) & 1) * 32 + (n & 31);
    int j = k & 7;
    BP[(((((ntb * 16 + kit) * 8 + ntl) * 4 + ksl) * 64 + lane) * 8) + j] = (f16)v;
}

// ---------------------------------------------------------------------------
// hq = query @ Wq + bq  (fp32). K split 4 ways, atomicAdd combine.
__global__ void hq_kernel(const float* __restrict__ query, const float* __restrict__ Wq,
                          const float* __restrict__ bq, float* __restrict__ hq) {
    int b = blockIdx.y;
    int h = (blockIdx.x & 3) * 256 + threadIdx.x;
    int v0 = (blockIdx.x >> 2) * 256;
    float acc = 0.f;
#pragma unroll 8
    for (int v = 0; v < 256; ++v)
        acc += query[b * 1024 + v0 + v] * Wq[(v0 + v) * 1024 + h];
    if (v0 == 0) acc += bq[h];
    atomicAdd(&hq[b * 1024 + h], acc);
}

// ---------------------------------------------------------------------------
// Fused 256x256x(K=1024) GEMM tile + tanh(hq+hv)·w row-reduction.
// Grid: 256 M-tiles x 4 N-blocks = 1024 blocks; 512 threads = 8 waves (2M x 4N),
// wave tile 128x64 (4 mt x 2 nt of 32x32). Double-buffered LDS:
//   A: 2 x [256][64] fp16 (32 KB each, XOR-swizzled slots), at offset 0
//   B: 2 x 32 KB fragment-ordered, at offset 65536.  Total 128 KB.
__launch_bounds__(512, 2)
__global__ void fused_main(const float* __restrict__ value, const f16* __restrict__ BP,
                           const float* __restrict__ hq, const float* __restrict__ wvec,
                           float* __restrict__ lpart) {
    extern __shared__ char smem[];

    int bid = blockIdx.x;
    int tile = (bid & 7) * 128 + (bid >> 3);   // XCD-chunked swizzle (1024 % 8 == 0)
    int Mt = tile >> 2, ntb = tile & 3;        // 4 N-blocks of one M-tile co-XCD
    int m0 = Mt << 8;                          // 256 rows
    int b = m0 >> 11, s0 = m0 & 2047;

    int tid = threadIdx.x;
    int w = tid >> 6, l = tid & 63;
    int wr = w >> 2, wc = w & 3;
    int l31 = l & 31, lg = l >> 5;

    // ---- per-thread A staging coords: thread t stages row t>>1, half (t&1)*32 floats
    int arow = tid >> 1, ahalf = tid & 1;
    const float* aga = value + (size_t)(m0 + arow) * 1024 + ahalf * 32;
    int aw_s0 = ahalf * 4;                     // first of 4 16B slots this thread writes
    int aw_base = arow * 128;                  // byte base of row in A tile
    int aw_xor = (arow & 7) << 4;

    // ---- B global base for this block
    const char* bg_base = (const char*)BP + (size_t)(ntb * 16) * 32768;

    // ---- loop-invariant LDS read offsets
    int a_off[4], a_xor[4];
#pragma unroll
    for (int mt = 0; mt < 4; ++mt) {
        int row = wr * 128 + mt * 32 + l31;
        a_off[mt] = row * 128;
        a_xor[mt] = (row & 7) << 4;
    }
    int b_off[2];
#pragma unroll
    for (int nt = 0; nt < 2; ++nt)
        b_off[nt] = (((wc * 2 + nt) * 4) * 64 + l) * 16;   // + ks*1024 per k-step

    const f32x16 fzero = {};
    f32x16 acc[4][2];
#pragma unroll
    for (int mt = 0; mt < 4; ++mt)
#pragma unroll
        for (int nt = 0; nt < 2; ++nt) acc[mt][nt] = fzero;

    // ---- prologue: stage iter 0 into buf 0
    {
#pragma unroll
        for (int i = 0; i < 4; ++i)
            gload_lds16(bg_base + i * 8192 + tid * 16, smem + 65536 + i * 8192 + tid * 16);
        float4 fa[8];
        const float4* ap = (const float4*)aga;
#pragma unroll
        for (int q = 0; q < 8; ++q) fa[q] = ap[q];
#pragma unroll
        for (int q2 = 0; q2 < 4; ++q2) {
            union { f16 h[8]; uint4 u; } pk;
            float4 p = fa[2 * q2], r = fa[2 * q2 + 1];
            pk.h[0] = (f16)p.x; pk.h[1] = (f16)p.y; pk.h[2] = (f16)p.z; pk.h[3] = (f16)p.w;
            pk.h[4] = (f16)r.x; pk.h[5] = (f16)r.y; pk.h[6] = (f16)r.z; pk.h[7] = (f16)r.w;
            int s = aw_s0 + q2;
            *(uint4*)(smem + aw_base + ((s << 4) ^ aw_xor)) = pk.u;
        }
        __syncthreads();
    }

    // ---- main K loop: 16 iters of BK=64, double-buffered
#pragma unroll 1
    for (int t = 0; t < 16; ++t) {
        int cur = t & 1;
        const char* Acur = smem + cur * 32768;
        const char* Bcur = smem + 65536 + cur * 32768;
        char* Anx = smem + (cur ^ 1) * 32768;
        char* Bnx = smem + 65536 + (cur ^ 1) * 32768;

        float4 fa[8];
        if (t < 15) {
            // issue next-iter staging loads BEFORE compute (latency hidden by MFMAs)
            const char* bsrc = bg_base + (size_t)(t + 1) * 32768;
#pragma unroll
            for (int i = 0; i < 4; ++i)
                gload_lds16(bsrc + i * 8192 + tid * 16, Bnx + i * 8192 + tid * 16);
            const float4* ap = (const float4*)(aga + (t + 1) * 64);
#pragma unroll
            for (int q = 0; q < 8; ++q) fa[q] = ap[q];
        }

        // compute current buffer: 4 k-steps x (4 A-reads + 2 B-reads + 8 MFMA)
#pragma unroll
        for (int ks = 0; ks < 4; ++ks) {
            f16x8 av[4], bv[2];
            int sl = (ks * 2 + lg) << 4;
#pragma unroll
            for (int mt = 0; mt < 4; ++mt)
                av[mt] = *(const f16x8*)(Acur + a_off[mt] + (sl ^ a_xor[mt]));
#pragma unroll
            for (int nt = 0; nt < 2; ++nt)
                bv[nt] = *(const f16x8*)(Bcur + b_off[nt] + ks * 1024);
#pragma unroll
            for (int mt = 0; mt < 4; ++mt)
#pragma unroll
                for (int nt = 0; nt < 2; ++nt)
                    acc[mt][nt] = __builtin_amdgcn_mfma_f32_32x32x16_f16(
                        av[mt], bv[nt], acc[mt][nt], 0, 0, 0);
        }

        if (t < 15) {
            // cvt + write next A tile (global loads have had the whole MFMA phase)
#pragma unroll
            for (int q2 = 0; q2 < 4; ++q2) {
                union { f16 h[8]; uint4 u; } pk;
                float4 p = fa[2 * q2], r = fa[2 * q2 + 1];
                pk.h[0] = (f16)p.x; pk.h[1] = (f16)p.y; pk.h[2] = (f16)p.z; pk.h[3] = (f16)p.w;
                pk.h[4] = (f16)r.x; pk.h[5] = (f16)r.y; pk.h[6] = (f16)r.z; pk.h[7] = (f16)r.w;
                int s = aw_s0 + q2;
                *(uint4*)(Anx + aw_base + ((s << 4) ^ aw_xor)) = pk.u;
            }
        }
        __syncthreads();
    }

    // ---- epilogue: t = tanh(hq + hv) * w, reduce over this block's 256 cols
    float hqv[2], wv2[2];
#pragma unroll
    for (int nt = 0; nt < 2; ++nt) {
        int h = ntb * 256 + wc * 64 + nt * 32 + l31;
        hqv[nt] = hq[b * 1024 + h];
        wv2[nt] = wvec[h];
    }

    float* part = (float*)smem;    // 4 KB: [wc(4)][row(256)]; safe after last barrier
#pragma unroll
    for (int mt = 0; mt < 4; ++mt) {
#pragma unroll
        for (int r = 0; r < 16; ++r) {
            float p = tanh_f(hqv[0] + acc[mt][0][r]) * wv2[0]
                    + tanh_f(hqv[1] + acc[mt][1][r]) * wv2[1];
            p += __shfl_xor(p, 1); p += __shfl_xor(p, 2); p += __shfl_xor(p, 4);
            p += __shfl_xor(p, 8); p += __shfl_xor(p, 16);
            if (l31 == 0) {
                int row = wr * 128 + mt * 32 + (r & 3) + ((r >> 2) << 3) + (lg << 2);
                part[wc * 256 + row] = p;
            }
        }
    }
    __syncthreads();
    if (tid < 256) {
        float s = part[tid] + part[256 + tid] + part[512 + tid] + part[768 + tid];
        lpart[((size_t)ntb * 32 + b) * 2048 + s0 + tid] = s;
    }
}

// ---------------------------------------------------------------------------
// Masked softmax over S=2048 per b, summing the 4 N-block logit partials.
__global__ void softmax_kernel(const float* __restrict__ lp, const int* __restrict__ mask,
                               float* __restrict__ out) {
    __shared__ float redm[16];
    __shared__ float reds[16];
    const int P = 32 * 2048;
    int b = blockIdx.x, t = threadIdx.x;
    int wid = t >> 6, lane = t & 63;
    int i0 = b * 2048 + t, i1 = i0 + 1024;
    float l0 = lp[i0] + lp[P + i0] + lp[2 * P + i0] + lp[3 * P + i0];
    float l1 = lp[i1] + lp[P + i1] + lp[2 * P + i1] + lp[3 * P + i1];
    float a0 = mask[i0] ? l0 : -1e9f;
    float a1 = mask[i1] ? l1 : -1e9f;
    float mx = fmaxf(a0, a1);
#pragma unroll
    for (int off = 1; off < 64; off <<= 1) mx = fmaxf(mx, __shfl_xor(mx, off));
    if (lane == 0) redm[wid] = mx;
    __syncthreads();
    mx = redm[0];
#pragma unroll
    for (int i = 1; i < 16; ++i) mx = fmaxf(mx, redm[i]);
    float e0 = __expf(a0 - mx), e1 = __expf(a1 - mx);
    float s = e0 + e1;
#pragma unroll
    for (int off = 1; off < 64; off <<= 1) s += __shfl_xor(s, off);
    if (lane == 0) reds[wid] = s;
    __syncthreads();
    float tot = 0.f;
#pragma unroll
    for (int i = 0; i < 16; ++i) tot += reds[i];
    float inv = 1.0f / tot;
    out[b * 2048 + t] = e0 * inv;
    out[b * 2048 + 1024 + t] = e1 * inv;
}

// ---------------------------------------------------------------------------
extern "C" void kernel_launch(void* const* d_in, const int* in_sizes, int n_in,
                              void* d_out, int out_size, void* d_ws, size_t ws_size,
                              hipStream_t stream) {
    const float* query = (const float*)d_in[0];
    const float* value = (const float*)d_in[1];
    const int*   mask  = (const int*)d_in[2];
    const float* Wq    = (const float*)d_in[3];
    const float* bq    = (const float*)d_in[4];
    const float* Wv    = (const float*)d_in[5];
    const float* wv    = (const float*)d_in[6];

    char* ws = (char*)d_ws;
    f16*   BP    = (f16*)(ws + WS_BP);
    float* hq    = (float*)(ws + WS_HQ);
    float* lpart = (float*)(ws + WS_LP);
    float* out   = (float*)d_out;

    hipMemsetAsync(hq, 0, BB * HH * sizeof(float), stream);
    pack_wv<<<(KK * HH) / 256, 256, 0, stream>>>(Wv, BP);
    hq_kernel<<<dim3(16, BB), 256, 0, stream>>>(query, Wq, bq, hq);
    fused_main<<<1024, 512, 131072, stream>>>(value, BP, hq, wv, lpart);
    softmax_kernel<<<BB, 1024, 0, stream>>>(lpart, mask, out);
}

// Round 2
// 237.717 us; speedup vs baseline: 1.2795x; 1.2795x over previous
//
#include <hip/hip_runtime.h>
#include <hip/hip_bf16.h>
#include <hip/hip_fp16.h>

typedef _Float16 f16;
typedef _Float16 f16x8 __attribute__((ext_vector_type(8)));
typedef float f32x16 __attribute__((ext_vector_type(16)));
typedef unsigned int u32;

// Problem sizes (fixed)
#define BB 32
#define SS 2048
#define HH 1024
#define KK 1024

// ws layout (bytes)
#define WS_BP 0                            // packed Wv fp16: 2 MB
#define WS_HQ (2u*1024u*1024u)             // hq fp32: 32*1024*4 = 128 KB
#define WS_LP (WS_HQ + 131072u)            // logits partials: 4*32*2048*4 = 1 MB

__device__ __forceinline__ float tanh_f(float x) {
    // tanh(x) = 1 - 2/(e^{2x}+1); safe at +/-inf of exp
    float e = __expf(2.0f * x);
    return 1.0f - 2.0f * __builtin_amdgcn_rcpf(e + 1.0f);
}

__device__ __forceinline__ void gload_lds16(const void* g, void* l) {
    __builtin_amdgcn_global_load_lds(
        (const __attribute__((address_space(1))) u32*)g,
        (__attribute__((address_space(3))) u32*)l, 16, 0, 0);
}

// ---------------------------------------------------------------------------
// Pack Wv [k][n] fp32 -> fragment-ordered fp16 for mfma_f32_32x32x16_f16 B-operand,
// grouped so each (N-block, BK=32 K-iter) slice is one contiguous 16 KB chunk:
// BP[ntb(4)][kit(32)][ntl(8)][ksl(2)][lane(64)][j(8)]
// frag layout: B[k][n], lane l: n = l&31, k = ks*16 + (l>>5)*8 + j
__global__ void pack_wv(const float* __restrict__ Wv, f16* __restrict__ BP) {
    int i = blockIdx.x * 256 + threadIdx.x;   // i = k*1024 + n
    int k = i >> 10, n = i & 1023;
    float v = Wv[i];
    int ntb = n >> 8;              // N-block (256 cols)
    int ntl = (n >> 5) & 7;        // local 32-col tile
    int kit = k >> 5;              // K-iter (BK=32)
    int ksl = (k >> 4) & 1;        // local k-step
    int lane = ((k >> 3) & 1) * 32 + (n & 31);
    int j = k & 7;
    BP[((((ntb * 32 + kit) * 8 + ntl) * 2 + ksl) * 64 + lane) * 8 + j] = (f16)v;
}

// ---------------------------------------------------------------------------
// hq = query @ Wq + bq  (fp32). K split 4 ways, atomicAdd combine.
__global__ void hq_kernel(const float* __restrict__ query, const float* __restrict__ Wq,
                          const float* __restrict__ bq, float* __restrict__ hq) {
    int b = blockIdx.y;
    int h = (blockIdx.x & 3) * 256 + threadIdx.x;
    int v0 = (blockIdx.x >> 2) * 256;
    float acc = 0.f;
#pragma unroll 8
    for (int v = 0; v < 256; ++v)
        acc += query[b * 1024 + v0 + v] * Wq[(v0 + v) * 1024 + h];
    if (v0 == 0) acc += bq[h];
    atomicAdd(&hq[b * 1024 + h], acc);
}

// ---------------------------------------------------------------------------
// Fused 256x256x(K=1024) GEMM tile + tanh(hq+hv)·w row-reduction.
// Grid: 256 M-tiles x 4 N-blocks = 1024 blocks; 1024 threads = 16 waves (4M x 4N),
// wave tile 64x64 (2mt x 2nt of 32x32) -> acc = 64 VGPR -> 4 waves/SIMD.
// LDS 64 KB: A dbuf 2x[256][32] f16 (16 KB, slot^((row>>1)&3) swizzle),
//            B dbuf 2x 16 KB fragment-ordered at +32768.
__launch_bounds__(1024, 4)
__global__ void fused_main(const float* __restrict__ value, const f16* __restrict__ BP,
                           const float* __restrict__ hq, const float* __restrict__ wvec,
                           float* __restrict__ lpart) {
    extern __shared__ char smem[];

    int bid = blockIdx.x;
    int tile = (bid & 7) * 128 + (bid >> 3);   // XCD-chunked swizzle (1024 % 8 == 0)
    int Mt = tile >> 2, ntb = tile & 3;        // 4 N-blocks of one M-tile co-XCD
    int m0 = Mt << 8;                          // 256 rows
    int b = m0 >> 11, s0 = m0 & 2047;

    int tid = threadIdx.x;
    int w = tid >> 6, l = tid & 63;
    int wm = w >> 2, wn = w & 3;
    int l31 = l & 31, lg = l >> 5;

    // ---- A staging coords: thread t stages row t>>2, 8 floats at col (t&3)*8
    int arow = tid >> 2;
    const float* aga = value + (size_t)(m0 + arow) * 1024 + (tid & 3) * 8;
    int aw_off = arow * 64 + ((((tid & 3) ^ ((arow >> 1) & 3))) << 4);

    // ---- B global src for this thread (per K-iter chunk = 16 KB)
    const char* bg = (const char*)BP + (size_t)ntb * (32u * 16384u) + tid * 16;

    // ---- loop-invariant fragment offsets
    int a_base[2], a_sw[2];
#pragma unroll
    for (int mt = 0; mt < 2; ++mt) {
        int row = wm * 64 + mt * 32 + l31;
        a_base[mt] = row * 64;
        a_sw[mt] = ((row >> 1) & 3) << 4;
    }
    int b_base[2];
#pragma unroll
    for (int nt = 0; nt < 2; ++nt)
        b_base[nt] = (wn * 2 + nt) * 2048 + l * 16;

    const f32x16 fzero = {};
    f32x16 acc[2][2];
#pragma unroll
    for (int mt = 0; mt < 2; ++mt)
#pragma unroll
        for (int nt = 0; nt < 2; ++nt) acc[mt][nt] = fzero;

    // ---- prologue: stage iter 0
    {
        const float4* ap = (const float4*)aga;
        float4 fa0 = ap[0], fa1 = ap[1];
        gload_lds16(bg, smem + 32768 + tid * 16);
        union { f16 h[8]; uint4 u; } pk;
        pk.h[0] = (f16)fa0.x; pk.h[1] = (f16)fa0.y; pk.h[2] = (f16)fa0.z; pk.h[3] = (f16)fa0.w;
        pk.h[4] = (f16)fa1.x; pk.h[5] = (f16)fa1.y; pk.h[6] = (f16)fa1.z; pk.h[7] = (f16)fa1.w;
        *(uint4*)(smem + aw_off) = pk.u;
        __syncthreads();
    }

    // ---- main K loop: 32 iters of BK=32, double-buffered
#pragma unroll 1
    for (int t = 0; t < 32; ++t) {
        const char* Acur = smem + (t & 1) * 16384;
        const char* Bcur = smem + 32768 + (t & 1) * 16384;
        char* Anx = smem + ((t + 1) & 1) * 16384;
        char* Bnx = smem + 32768 + ((t + 1) & 1) * 16384;

        float4 fa0, fa1;
        if (t < 31) {
            // issue next-iter loads first (latency hidden under the MFMA phase)
            const float4* ap = (const float4*)(aga + (t + 1) * 32);
            fa0 = ap[0]; fa1 = ap[1];
            gload_lds16(bg + (size_t)(t + 1) * 16384, Bnx + tid * 16);
        }

        // compute current buffer: 2 k-steps x (2 A + 2 B reads + 4 MFMA)
#pragma unroll
        for (int ks = 0; ks < 2; ++ks) {
            int sl = (ks * 2 + lg) << 4;
            f16x8 av0 = *(const f16x8*)(Acur + a_base[0] + (sl ^ a_sw[0]));
            f16x8 av1 = *(const f16x8*)(Acur + a_base[1] + (sl ^ a_sw[1]));
            f16x8 bv0 = *(const f16x8*)(Bcur + b_base[0] + ks * 1024);
            f16x8 bv1 = *(const f16x8*)(Bcur + b_base[1] + ks * 1024);
            acc[0][0] = __builtin_amdgcn_mfma_f32_32x32x16_f16(av0, bv0, acc[0][0], 0, 0, 0);
            acc[0][1] = __builtin_amdgcn_mfma_f32_32x32x16_f16(av0, bv1, acc[0][1], 0, 0, 0);
            acc[1][0] = __builtin_amdgcn_mfma_f32_32x32x16_f16(av1, bv0, acc[1][0], 0, 0, 0);
            acc[1][1] = __builtin_amdgcn_mfma_f32_32x32x16_f16(av1, bv1, acc[1][1], 0, 0, 0);
        }

        if (t < 31) {
            union { f16 h[8]; uint4 u; } pk;
            pk.h[0] = (f16)fa0.x; pk.h[1] = (f16)fa0.y; pk.h[2] = (f16)fa0.z; pk.h[3] = (f16)fa0.w;
            pk.h[4] = (f16)fa1.x; pk.h[5] = (f16)fa1.y; pk.h[6] = (f16)fa1.z; pk.h[7] = (f16)fa1.w;
            *(uint4*)(Anx + aw_off) = pk.u;
        }
        __syncthreads();
    }

    // ---- epilogue: t = tanh(hq + hv) * w, reduce over this block's 256 cols
    int h0 = ntb * 256 + wn * 64 + l31;   // nt = 0
    int h1 = h0 + 32;                     // nt = 1
    float hq0 = hq[b * 1024 + h0], hq1 = hq[b * 1024 + h1];
    float w0 = wvec[h0], w1 = wvec[h1];

    float* part = (float*)smem;   // 4 KB [wn(4)][row(256)]; A-buffers dead now
#pragma unroll
    for (int mt = 0; mt < 2; ++mt) {
#pragma unroll
        for (int r = 0; r < 16; ++r) {
            float p = tanh_f(hq0 + acc[mt][0][r]) * w0
                    + tanh_f(hq1 + acc[mt][1][r]) * w1;
            p += __shfl_xor(p, 1); p += __shfl_xor(p, 2); p += __shfl_xor(p, 4);
            p += __shfl_xor(p, 8); p += __shfl_xor(p, 16);
            if (l31 == 0) {
                int row = wm * 64 + mt * 32 + (r & 3) + ((r >> 2) << 3) + (lg << 2);
                part[wn * 256 + row] = p;
            }
        }
    }
    __syncthreads();
    if (tid < 256) {
        float s = part[tid] + part[256 + tid] + part[512 + tid] + part[768 + tid];
        lpart[((size_t)ntb * 32 + b) * 2048 + s0 + tid] = s;
    }
}

// ---------------------------------------------------------------------------
// Masked softmax over S=2048 per b, summing the 4 N-block logit partials.
__global__ void softmax_kernel(const float* __restrict__ lp, const int* __restrict__ mask,
                               float* __restrict__ out) {
    __shared__ float redm[16];
    __shared__ float reds[16];
    const int P = 32 * 2048;
    int b = blockIdx.x, t = threadIdx.x;
    int wid = t >> 6, lane = t & 63;
    int i0 = b * 2048 + t, i1 = i0 + 1024;
    float l0 = lp[i0] + lp[P + i0] + lp[2 * P + i0] + lp[3 * P + i0];
    float l1 = lp[i1] + lp[P + i1] + lp[2 * P + i1] + lp[3 * P + i1];
    float a0 = mask[i0] ? l0 : -1e9f;
    float a1 = mask[i1] ? l1 : -1e9f;
    float mx = fmaxf(a0, a1);
#pragma unroll
    for (int off = 1; off < 64; off <<= 1) mx = fmaxf(mx, __shfl_xor(mx, off));
    if (lane == 0) redm[wid] = mx;
    __syncthreads();
    mx = redm[0];
#pragma unroll
    for (int i = 1; i < 16; ++i) mx = fmaxf(mx, redm[i]);
    float e0 = __expf(a0 - mx), e1 = __expf(a1 - mx);
    float s = e0 + e1;
#pragma unroll
    for (int off = 1; off < 64; off <<= 1) s += __shfl_xor(s, off);
    if (lane == 0) reds[wid] = s;
    __syncthreads();
    float tot = 0.f;
#pragma unroll
    for (int i = 0; i < 16; ++i) tot += reds[i];
    float inv = 1.0f / tot;
    out[b * 2048 + t] = e0 * inv;
    out[b * 2048 + 1024 + t] = e1 * inv;
}

// ---------------------------------------------------------------------------
extern "C" void kernel_launch(void* const* d_in, const int* in_sizes, int n_in,
                              void* d_out, int out_size, void* d_ws, size_t ws_size,
                              hipStream_t stream) {
    const float* query = (const float*)d_in[0];
    const float* value = (const float*)d_in[1];
    const int*   mask  = (const int*)d_in[2];
    const float* Wq    = (const float*)d_in[3];
    const float* bq    = (const float*)d_in[4];
    const float* Wv    = (const float*)d_in[5];
    const float* wv    = (const float*)d_in[6];

    char* ws = (char*)d_ws;
    f16*   BP    = (f16*)(ws + WS_BP);
    float* hq    = (float*)(ws + WS_HQ);
    float* lpart = (float*)(ws + WS_LP);
    float* out   = (float*)d_out;

    hipMemsetAsync(hq, 0, BB * HH * sizeof(float), stream);
    pack_wv<<<(KK * HH) / 256, 256, 0, stream>>>(Wv, BP);
    hq_kernel<<<dim3(16, BB), 256, 0, stream>>>(query, Wq, bq, hq);
    fused_main<<<1024, 1024, 65536, stream>>>(value, BP, hq, wv, lpart);
    softmax_kernel<<<BB, 1024, 0, stream>>>(lpart, mask, out);
}

// Round 3
// 228.564 us; speedup vs baseline: 1.3307x; 1.0400x over previous
//
#include <hip/hip_runtime.h>
#include <hip/hip_bf16.h>
#include <hip/hip_fp16.h>

typedef _Float16 f16;
typedef _Float16 f16x8 __attribute__((ext_vector_type(8)));
typedef float f32x16 __attribute__((ext_vector_type(16)));
typedef unsigned int u32;

// Problem sizes (fixed)
#define BB 32
#define SS 2048
#define HH 1024
#define KK 1024

// ws layout (bytes)
#define WS_BP 0                            // packed Wv fp16: 2 MB
#define WS_HQ (2u*1024u*1024u)             // hq fp32: 32*1024*4 = 128 KB
#define WS_LP (WS_HQ + 131072u)            // logits partials: 4*32*2048*4 = 1 MB

__device__ __forceinline__ float tanh_f(float x) {
    // tanh(x) = 1 - 2/(e^{2x}+1); safe at +/-inf of exp
    float e = __expf(2.0f * x);
    return 1.0f - 2.0f * __builtin_amdgcn_rcpf(e + 1.0f);
}

__device__ __forceinline__ void gload_lds16(const void* g, void* l) {
    __builtin_amdgcn_global_load_lds(
        (const __attribute__((address_space(1))) u32*)g,
        (__attribute__((address_space(3))) u32*)l, 16, 0, 0);
}

// ---------------------------------------------------------------------------
// Pack Wv [k][n] fp32 -> fragment-ordered fp16 for mfma_f32_32x32x16_f16 B-operand,
// grouped so each (N-block, BK=32 K-iter) slice is one contiguous 16 KB chunk:
// BP[ntb(4)][kit(32)][ntl(8)][ksl(2)][lane(64)][j(8)]
// frag layout: B[k][n], lane l: n = l&31, k = ks*16 + (l>>5)*8 + j
__global__ void pack_wv(const float* __restrict__ Wv, f16* __restrict__ BP) {
    int i = blockIdx.x * 256 + threadIdx.x;   // i = k*1024 + n
    int k = i >> 10, n = i & 1023;
    float v = Wv[i];
    int ntb = n >> 8;              // N-block (256 cols)
    int ntl = (n >> 5) & 7;        // local 32-col tile
    int kit = k >> 5;              // K-iter (BK=32)
    int ksl = (k >> 4) & 1;        // local k-step
    int lane = ((k >> 3) & 1) * 32 + (n & 31);
    int j = k & 7;
    BP[((((ntb * 32 + kit) * 8 + ntl) * 2 + ksl) * 64 + lane) * 8 + j] = (f16)v;
}

// ---------------------------------------------------------------------------
// hq = query @ Wq + bq  (fp32). K split 4 ways, atomicAdd combine.
__global__ void hq_kernel(const float* __restrict__ query, const float* __restrict__ Wq,
                          const float* __restrict__ bq, float* __restrict__ hq) {
    int b = blockIdx.y;
    int h = (blockIdx.x & 3) * 256 + threadIdx.x;
    int v0 = (blockIdx.x >> 2) * 256;
    float acc = 0.f;
#pragma unroll 8
    for (int v = 0; v < 256; ++v)
        acc += query[b * 1024 + v0 + v] * Wq[(v0 + v) * 1024 + h];
    if (v0 == 0) acc += bq[h];
    atomicAdd(&hq[b * 1024 + h], acc);
}

// ---------------------------------------------------------------------------
// Fused 128x256x(K=1024) GEMM tile + tanh(hq+hv)·w row-reduction.
// Grid: 512 M-tiles x 4 N-blocks = 2048 blocks; 512 threads = 8 waves (2M x 4N),
// wave tile 64x64 (2mt x 2nt of 32x32) -> acc = 64 regs -> 4 waves/SIMD,
// and ONLY 8 waves per block -> 2 blocks/CU co-resident (cross-block overlap
// covers barrier drains + A-load HBM latency; the m97 mechanism).
// LDS 48 KB: A dbuf 2x[128][32] f16 (8 KB each, slot^((row>>1)&3) swizzle) at 0,
//            B dbuf 2x 16 KB fragment-ordered at +16384.
__launch_bounds__(512, 4)
__global__ void fused_main(const float* __restrict__ value, const f16* __restrict__ BP,
                           const float* __restrict__ hq, const float* __restrict__ wvec,
                           float* __restrict__ lpart) {
    extern __shared__ char smem[];

    int bid = blockIdx.x;
    int tile = (bid & 7) * 256 + (bid >> 3);   // XCD-chunked swizzle (2048 % 8 == 0)
    int Mt = tile >> 2, ntb = tile & 3;        // 4 N-blocks of one M-tile co-XCD
    int m0 = Mt << 7;                          // 128 rows
    int b = m0 >> 11, s0 = m0 & 2047;

    int tid = threadIdx.x;
    int w = tid >> 6, l = tid & 63;
    int wm = w >> 2, wn = w & 3;
    int l31 = l & 31, lg = l >> 5;

    // ---- A staging coords: thread t stages row t>>2 (0..127), 8 floats at col (t&3)*8
    int arow = tid >> 2;
    const float* aga = value + (size_t)(m0 + arow) * 1024 + (tid & 3) * 8;
    int aw_off = arow * 64 + ((((tid & 3) ^ ((arow >> 1) & 3))) << 4);

    // ---- B global src for this thread (per K-iter chunk = 16 KB, 2 gloads/thread)
    const char* bg = (const char*)BP + (size_t)ntb * (32u * 16384u) + tid * 16;

    // ---- loop-invariant fragment offsets
    int a_base[2], a_sw[2];
#pragma unroll
    for (int mt = 0; mt < 2; ++mt) {
        int row = wm * 64 + mt * 32 + l31;
        a_base[mt] = row * 64;
        a_sw[mt] = ((row >> 1) & 3) << 4;
    }
    int b_base[2];
#pragma unroll
    for (int nt = 0; nt < 2; ++nt)
        b_base[nt] = (wn * 2 + nt) * 2048 + l * 16;

    const f32x16 fzero = {};
    f32x16 acc[2][2];
#pragma unroll
    for (int mt = 0; mt < 2; ++mt)
#pragma unroll
        for (int nt = 0; nt < 2; ++nt) acc[mt][nt] = fzero;

    // ---- prologue: stage iter 0
    {
        const float4* ap = (const float4*)aga;
        float4 fa0 = ap[0], fa1 = ap[1];
        gload_lds16(bg, smem + 16384 + tid * 16);
        gload_lds16(bg + 8192, smem + 16384 + 8192 + tid * 16);
        union { f16 h[8]; uint4 u; } pk;
        pk.h[0] = (f16)fa0.x; pk.h[1] = (f16)fa0.y; pk.h[2] = (f16)fa0.z; pk.h[3] = (f16)fa0.w;
        pk.h[4] = (f16)fa1.x; pk.h[5] = (f16)fa1.y; pk.h[6] = (f16)fa1.z; pk.h[7] = (f16)fa1.w;
        *(uint4*)(smem + aw_off) = pk.u;
        __syncthreads();
    }

    // ---- main K loop: 32 iters of BK=32, double-buffered
#pragma unroll 1
    for (int t = 0; t < 32; ++t) {
        const char* Acur = smem + (t & 1) * 8192;
        const char* Bcur = smem + 16384 + (t & 1) * 16384;
        char* Anx = smem + ((t + 1) & 1) * 8192;
        char* Bnx = smem + 16384 + ((t + 1) & 1) * 16384;

        float4 fa0, fa1;
        if (t < 31) {
            // issue next-iter loads first (latency hidden under the MFMA phase
            // of this block AND the co-resident block's compute)
            const float4* ap = (const float4*)(aga + (t + 1) * 32);
            fa0 = ap[0]; fa1 = ap[1];
            const char* bsrc = bg + (size_t)(t + 1) * 16384;
            gload_lds16(bsrc, Bnx + tid * 16);
            gload_lds16(bsrc + 8192, Bnx + 8192 + tid * 16);
        }

        // compute current buffer: 2 k-steps x (2 A + 2 B reads + 4 MFMA)
#pragma unroll
        for (int ks = 0; ks < 2; ++ks) {
            int sl = (ks * 2 + lg) << 4;
            f16x8 av0 = *(const f16x8*)(Acur + a_base[0] + (sl ^ a_sw[0]));
            f16x8 av1 = *(const f16x8*)(Acur + a_base[1] + (sl ^ a_sw[1]));
            f16x8 bv0 = *(const f16x8*)(Bcur + b_base[0] + ks * 1024);
            f16x8 bv1 = *(const f16x8*)(Bcur + b_base[1] + ks * 1024);
            acc[0][0] = __builtin_amdgcn_mfma_f32_32x32x16_f16(av0, bv0, acc[0][0], 0, 0, 0);
            acc[0][1] = __builtin_amdgcn_mfma_f32_32x32x16_f16(av0, bv1, acc[0][1], 0, 0, 0);
            acc[1][0] = __builtin_amdgcn_mfma_f32_32x32x16_f16(av1, bv0, acc[1][0], 0, 0, 0);
            acc[1][1] = __builtin_amdgcn_mfma_f32_32x32x16_f16(av1, bv1, acc[1][1], 0, 0, 0);
        }

        if (t < 31) {
            union { f16 h[8]; uint4 u; } pk;
            pk.h[0] = (f16)fa0.x; pk.h[1] = (f16)fa0.y; pk.h[2] = (f16)fa0.z; pk.h[3] = (f16)fa0.w;
            pk.h[4] = (f16)fa1.x; pk.h[5] = (f16)fa1.y; pk.h[6] = (f16)fa1.z; pk.h[7] = (f16)fa1.w;
            *(uint4*)(Anx + aw_off) = pk.u;
        }
        __syncthreads();
    }

    // ---- epilogue: t = tanh(hq + hv) * w, reduce over this block's 256 cols
    int h0 = ntb * 256 + wn * 64 + l31;   // nt = 0
    int h1 = h0 + 32;                     // nt = 1
    float hq0 = hq[b * 1024 + h0], hq1 = hq[b * 1024 + h1];
    float w0 = wvec[h0], w1 = wvec[h1];

    float* part = (float*)smem;   // 2 KB [wn(4)][row(128)]; A-buffers dead now
#pragma unroll
    for (int mt = 0; mt < 2; ++mt) {
#pragma unroll
        for (int r = 0; r < 16; ++r) {
            float p = tanh_f(hq0 + acc[mt][0][r]) * w0
                    + tanh_f(hq1 + acc[mt][1][r]) * w1;
            p += __shfl_xor(p, 1); p += __shfl_xor(p, 2); p += __shfl_xor(p, 4);
            p += __shfl_xor(p, 8); p += __shfl_xor(p, 16);
            if (l31 == 0) {
                int row = wm * 64 + mt * 32 + (r & 3) + ((r >> 2) << 3) + (lg << 2);
                part[wn * 128 + row] = p;
            }
        }
    }
    __syncthreads();
    if (tid < 128) {
        float s = part[tid] + part[128 + tid] + part[256 + tid] + part[384 + tid];
        lpart[((size_t)ntb * 32 + b) * 2048 + s0 + tid] = s;
    }
}

// ---------------------------------------------------------------------------
// Masked softmax over S=2048 per b, summing the 4 N-block logit partials.
__global__ void softmax_kernel(const float* __restrict__ lp, const int* __restrict__ mask,
                               float* __restrict__ out) {
    __shared__ float redm[16];
    __shared__ float reds[16];
    const int P = 32 * 2048;
    int b = blockIdx.x, t = threadIdx.x;
    int wid = t >> 6, lane = t & 63;
    int i0 = b * 2048 + t, i1 = i0 + 1024;
    float l0 = lp[i0] + lp[P + i0] + lp[2 * P + i0] + lp[3 * P + i0];
    float l1 = lp[i1] + lp[P + i1] + lp[2 * P + i1] + lp[3 * P + i1];
    float a0 = mask[i0] ? l0 : -1e9f;
    float a1 = mask[i1] ? l1 : -1e9f;
    float mx = fmaxf(a0, a1);
#pragma unroll
    for (int off = 1; off < 64; off <<= 1) mx = fmaxf(mx, __shfl_xor(mx, off));
    if (lane == 0) redm[wid] = mx;
    __syncthreads();
    mx = redm[0];
#pragma unroll
    for (int i = 1; i < 16; ++i) mx = fmaxf(mx, redm[i]);
    float e0 = __expf(a0 - mx), e1 = __expf(a1 - mx);
    float s = e0 + e1;
#pragma unroll
    for (int off = 1; off < 64; off <<= 1) s += __shfl_xor(s, off);
    if (lane == 0) reds[wid] = s;
    __syncthreads();
    float tot = 0.f;
#pragma unroll
    for (int i = 0; i < 16; ++i) tot += reds[i];
    float inv = 1.0f / tot;
    out[b * 2048 + t] = e0 * inv;
    out[b * 2048 + 1024 + t] = e1 * inv;
}

// ---------------------------------------------------------------------------
extern "C" void kernel_launch(void* const* d_in, const int* in_sizes, int n_in,
                              void* d_out, int out_size, void* d_ws, size_t ws_size,
                              hipStream_t stream) {
    const float* query = (const float*)d_in[0];
    const float* value = (const float*)d_in[1];
    const int*   mask  = (const int*)d_in[2];
    const float* Wq    = (const float*)d_in[3];
    const float* bq    = (const float*)d_in[4];
    const float* Wv    = (const float*)d_in[5];
    const float* wv    = (const float*)d_in[6];

    char* ws = (char*)d_ws;
    f16*   BP    = (f16*)(ws + WS_BP);
    float* hq    = (float*)(ws + WS_HQ);
    float* lpart = (float*)(ws + WS_LP);
    float* out   = (float*)d_out;

    hipMemsetAsync(hq, 0, BB * HH * sizeof(float), stream);
    pack_wv<<<(KK * HH) / 256, 256, 0, stream>>>(Wv, BP);
    hq_kernel<<<dim3(16, BB), 256, 0, stream>>>(query, Wq, bq, hq);
    fused_main<<<2048, 512, 49152, stream>>>(value, BP, hq, wv, lpart);
    softmax_kernel<<<BB, 1024, 0, stream>>>(lpart, mask, out);
}

// Round 5
// 217.338 us; speedup vs baseline: 1.3995x; 1.0517x over previous
//
#include <hip/hip_runtime.h>
#include <hip/hip_bf16.h>
#include <hip/hip_fp16.h>

typedef _Float16 f16;
typedef _Float16 f16x8 __attribute__((ext_vector_type(8)));
typedef float f32x16 __attribute__((ext_vector_type(16)));
typedef unsigned int u32;

// Problem sizes (fixed)
#define BB 32
#define SS 2048
#define HH 1024
#define KK 1024

// ws layout (bytes)
#define WS_BP 0                            // packed Wv fp16: 2 MB
#define WS_HQ (2u*1024u*1024u)             // hq fp32: 32*1024*4 = 128 KB
#define WS_LP (WS_HQ + 131072u)            // logits partials: 4*32*2048*4 = 1 MB

__device__ __forceinline__ float tanh_f(float x) {
    // tanh(x) = 1 - 2/(e^{2x}+1); safe at +/-inf of exp
    float e = __expf(2.0f * x);
    return 1.0f - 2.0f * __builtin_amdgcn_rcpf(e + 1.0f);
}

__device__ __forceinline__ void gload_lds16(const void* g, void* l) {
    __builtin_amdgcn_global_load_lds(
        (const __attribute__((address_space(1))) u32*)g,
        (__attribute__((address_space(3))) u32*)l, 16, 0, 0);
}

// fp32x8 -> fp16x8 cvt + swizzled 16B LDS store (macro params must NOT be
// named x/y/z/w: the preprocessor substitutes them inside member accesses).
__device__ __forceinline__ void write_a16(char* dst, int off, float4 va, float4 vb) {
    union { f16 h[8]; uint4 u; } pk;
    pk.h[0] = (f16)va.x; pk.h[1] = (f16)va.y; pk.h[2] = (f16)va.z; pk.h[3] = (f16)va.w;
    pk.h[4] = (f16)vb.x; pk.h[5] = (f16)vb.y; pk.h[6] = (f16)vb.z; pk.h[7] = (f16)vb.w;
    *(uint4*)(dst + off) = pk.u;
}

// ---------------------------------------------------------------------------
// Pack Wv [k][n] fp32 -> fragment-ordered fp16 for mfma_f32_32x32x16_f16 B-operand,
// grouped so each (N-block, BK=32 K-iter) slice is one contiguous 16 KB chunk:
// BP[ntb(4)][kit(32)][ntl(8)][ksl(2)][lane(64)][j(8)]
// frag layout: B[k][n], lane l: n = l&31, k = ks*16 + (l>>5)*8 + j
__global__ void pack_wv(const float* __restrict__ Wv, f16* __restrict__ BP) {
    int i = blockIdx.x * 256 + threadIdx.x;   // i = k*1024 + n
    int k = i >> 10, n = i & 1023;
    float v = Wv[i];
    int ntb = n >> 8;              // N-block (256 cols)
    int ntl = (n >> 5) & 7;        // local 32-col tile
    int kit = k >> 5;              // K-iter (BK=32)
    int ksl = (k >> 4) & 1;        // local k-step
    int lane = ((k >> 3) & 1) * 32 + (n & 31);
    int j = k & 7;
    BP[((((ntb * 32 + kit) * 8 + ntl) * 2 + ksl) * 64 + lane) * 8 + j] = (f16)v;
}

// ---------------------------------------------------------------------------
// hq = query @ Wq + bq  (fp32). K split 4 ways, atomicAdd combine.
__global__ void hq_kernel(const float* __restrict__ query, const float* __restrict__ Wq,
                          const float* __restrict__ bq, float* __restrict__ hq) {
    int b = blockIdx.y;
    int h = (blockIdx.x & 3) * 256 + threadIdx.x;
    int v0 = (blockIdx.x >> 2) * 256;
    float acc = 0.f;
#pragma unroll 8
    for (int v = 0; v < 256; ++v)
        acc += query[b * 1024 + v0 + v] * Wq[(v0 + v) * 1024 + h];
    if (v0 == 0) acc += bq[h];
    atomicAdd(&hq[b * 1024 + h], acc);
}

// ---------------------------------------------------------------------------
// Fused 128x256x(K=1024) GEMM tile + tanh(hq+hv)·w row-reduction.
// Same geometry as round 3 (2 blocks/CU, 8 waves, 64x64 wave tiles). New sync
// structure: raw s_barrier + counted vmcnt(2); A-value global loads pipelined
// 2 iterations deep in registers so the ~900-cyc HBM latency is never drained
// at a barrier (the full-drain __syncthreads was the round-3 stall).
// LDS 48 KB: A0[0,8K) A1[8K,16K) (swizzled [128][32] f16), B0[16K,32K) B1[32K,48K).
__launch_bounds__(512, 4)
__global__ void fused_main(const float* __restrict__ value, const f16* __restrict__ BP,
                           const float* __restrict__ hq, const float* __restrict__ wvec,
                           float* __restrict__ lpart) {
    extern __shared__ char smem[];
    char* A0 = smem;
    char* A1 = smem + 8192;
    char* B0 = smem + 16384;
    char* B1 = smem + 32768;

    int bid = blockIdx.x;
    int tile = (bid & 7) * 256 + (bid >> 3);   // XCD-chunked swizzle (2048 % 8 == 0)
    int Mt = tile >> 2, ntb = tile & 3;        // 4 N-blocks of one M-tile co-XCD
    int m0 = Mt << 7;                          // 128 rows
    int b = m0 >> 11, s0 = m0 & 2047;

    int tid = threadIdx.x;
    int w = tid >> 6, l = tid & 63;
    int wm = w >> 2, wn = w & 3;
    int l31 = l & 31, lg = l >> 5;

    // ---- A staging coords: thread t stages row t>>2 (0..127), 8 floats at col (t&3)*8
    int arow = tid >> 2;
    const float* aga = value + (size_t)(m0 + arow) * 1024 + (tid & 3) * 8;
    int aw_off = arow * 64 + ((((tid & 3) ^ ((arow >> 1) & 3))) << 4);

    // ---- B global src for this thread (per K-iter chunk = 16 KB, 2 gloads/thread)
    const char* bg = (const char*)BP + (size_t)ntb * (32u * 16384u) + tid * 16;

    // ---- loop-invariant fragment offsets
    int a_base[2], a_sw[2];
#pragma unroll
    for (int mt = 0; mt < 2; ++mt) {
        int row = wm * 64 + mt * 32 + l31;
        a_base[mt] = row * 64;
        a_sw[mt] = ((row >> 1) & 3) << 4;
    }
    int b_base[2];
#pragma unroll
    for (int nt = 0; nt < 2; ++nt)
        b_base[nt] = (wn * 2 + nt) * 2048 + l * 16;

    const f32x16 fzero = {};
    f32x16 acc[2][2];
#pragma unroll
    for (int mt = 0; mt < 2; ++mt)
#pragma unroll
        for (int nt = 0; nt < 2; ++nt) acc[mt][nt] = fzero;

#define COMPUTE(Acur, Bcur) do { \
        __builtin_amdgcn_s_setprio(1); \
        _Pragma("unroll") \
        for (int ks = 0; ks < 2; ++ks) { \
            int sl = (ks * 2 + lg) << 4; \
            f16x8 av0 = *(const f16x8*)((Acur) + a_base[0] + (sl ^ a_sw[0])); \
            f16x8 av1 = *(const f16x8*)((Acur) + a_base[1] + (sl ^ a_sw[1])); \
            f16x8 bv0 = *(const f16x8*)((Bcur) + b_base[0] + ks * 1024); \
            f16x8 bv1 = *(const f16x8*)((Bcur) + b_base[1] + ks * 1024); \
            acc[0][0] = __builtin_amdgcn_mfma_f32_32x32x16_f16(av0, bv0, acc[0][0], 0, 0, 0); \
            acc[0][1] = __builtin_amdgcn_mfma_f32_32x32x16_f16(av0, bv1, acc[0][1], 0, 0, 0); \
            acc[1][0] = __builtin_amdgcn_mfma_f32_32x32x16_f16(av1, bv0, acc[1][0], 0, 0, 0); \
            acc[1][1] = __builtin_amdgcn_mfma_f32_32x32x16_f16(av1, bv1, acc[1][1], 0, 0, 0); \
        } \
        __builtin_amdgcn_s_setprio(0); \
    } while (0)

    float4 fe0, fe1, fo0, fo1;   // 2-deep A register pipeline (even/odd tiles)

    // ---- prologue: B0 gloads; A tile0 -> LDS A0; A tile1 -> regs (fo)
    {
        gload_lds16(bg, B0 + tid * 16);
        gload_lds16(bg + 8192, B0 + 8192 + tid * 16);
        __builtin_amdgcn_sched_barrier(0);
        const float4* ap = (const float4*)aga;
        float4 e0 = ap[0], e1 = ap[1];          // tile 0 (auto vmcnt drains B0 too)
        write_a16(A0, aw_off, e0, e1);
        const float4* ap1 = (const float4*)(aga + 32);
        fo0 = ap1[0]; fo1 = ap1[1];             // tile 1, stays in flight
        asm volatile("s_waitcnt lgkmcnt(0)" ::: "memory");
        __builtin_amdgcn_s_barrier();
    }

    // ---- main K loop: 16 x (even iter t=2tt, odd iter t=2tt+1), BK=32 each
#pragma unroll 1
    for (int tt = 0; tt < 16; ++tt) {
        // ===== even iter t = 2tt: compute (A0,B0); stage B(t+1)->B1, A(t+2)->fe
        {
            const char* bsrc = bg + (size_t)(2 * tt + 1) * 16384;
            gload_lds16(bsrc, B1 + tid * 16);
            gload_lds16(bsrc + 8192, B1 + 8192 + tid * 16);
            __builtin_amdgcn_sched_barrier(0);
            int xa = 2 * tt + 2; if (xa > 31) xa = 31;   // clamped dummy at tail
            const float4* ap = (const float4*)(aga + xa * 32);
            fe0 = ap[0]; fe1 = ap[1];
            __builtin_amdgcn_sched_barrier(0);
            COMPUTE(A0, B0);
            write_a16(A1, aw_off, fo0, fo1);     // tile 2tt+1 (auto vmcnt waits)
            asm volatile("s_waitcnt vmcnt(2) lgkmcnt(0)" ::: "memory");
            __builtin_amdgcn_s_barrier();
        }
        // ===== odd iter t = 2tt+1: compute (A1,B1); stage B(t+1)->B0, A(t+2)->fo
        {
            int xb = 2 * tt + 2; if (xb > 31) xb = 31;   // dup at tail, dest unread
            const char* bsrc = bg + (size_t)xb * 16384;
            gload_lds16(bsrc, B0 + tid * 16);
            gload_lds16(bsrc + 8192, B0 + 8192 + tid * 16);
            __builtin_amdgcn_sched_barrier(0);
            int xc = 2 * tt + 3; if (xc > 31) xc = 31;
            const float4* ap = (const float4*)(aga + xc * 32);
            fo0 = ap[0]; fo1 = ap[1];
            __builtin_amdgcn_sched_barrier(0);
            COMPUTE(A1, B1);
            if (tt < 15) write_a16(A0, aw_off, fe0, fe1);   // tile 2tt+2
            asm volatile("s_waitcnt vmcnt(2) lgkmcnt(0)" ::: "memory");
            __builtin_amdgcn_s_barrier();
        }
    }

    // ---- epilogue: t = tanh(hq + hv) * w, pair-folded col reduction
    int h0 = ntb * 256 + wn * 64 + l31;   // nt = 0
    int h1 = h0 + 32;                     // nt = 1
    float hq0 = hq[b * 1024 + h0], hq1 = hq[b * 1024 + h1];
    float w0 = wvec[h0], w1 = wvec[h1];

    float* part = (float*)smem;   // 2 KB [wn(4)][row(128)] in dead A0 region
#pragma unroll
    for (int mt = 0; mt < 2; ++mt) {
#pragma unroll
        for (int i = 0; i < 8; ++i) {
            float pa = tanh_f(hq0 + acc[mt][0][2 * i]) * w0
                     + tanh_f(hq1 + acc[mt][1][2 * i]) * w1;
            float pb = tanh_f(hq0 + acc[mt][0][2 * i + 1]) * w0
                     + tanh_f(hq1 + acc[mt][1][2 * i + 1]) * w1;
            float ea = __shfl_xor(pa, 1), eb = __shfl_xor(pb, 1);
            float g = (l & 1) ? (pb + eb) : (pa + ea);
            g += __shfl_xor(g, 2); g += __shfl_xor(g, 4);
            g += __shfl_xor(g, 8); g += __shfl_xor(g, 16);
            if (l31 < 2) {
                int r = 2 * i + (l31 & 1);
                int row = wm * 64 + mt * 32 + (r & 3) + ((r >> 2) << 3) + (lg << 2);
                part[wn * 128 + row] = g;
            }
        }
    }
    __syncthreads();
    if (tid < 128) {
        float s = part[tid] + part[128 + tid] + part[256 + tid] + part[384 + tid];
        lpart[((size_t)ntb * 32 + b) * 2048 + s0 + tid] = s;
    }
#undef COMPUTE
}

// ---------------------------------------------------------------------------
// Masked softmax over S=2048 per b, summing the 4 N-block logit partials.
__global__ void softmax_kernel(const float* __restrict__ lp, const int* __restrict__ mask,
                               float* __restrict__ out) {
    __shared__ float redm[16];
    __shared__ float reds[16];
    const int P = 32 * 2048;
    int b = blockIdx.x, t = threadIdx.x;
    int wid = t >> 6, lane = t & 63;
    int i0 = b * 2048 + t, i1 = i0 + 1024;
    float l0 = lp[i0] + lp[P + i0] + lp[2 * P + i0] + lp[3 * P + i0];
    float l1 = lp[i1] + lp[P + i1] + lp[2 * P + i1] + lp[3 * P + i1];
    float a0 = mask[i0] ? l0 : -1e9f;
    float a1 = mask[i1] ? l1 : -1e9f;
    float mx = fmaxf(a0, a1);
#pragma unroll
    for (int off = 1; off < 64; off <<= 1) mx = fmaxf(mx, __shfl_xor(mx, off));
    if (lane == 0) redm[wid] = mx;
    __syncthreads();
    mx = redm[0];
#pragma unroll
    for (int i = 1; i < 16; ++i) mx = fmaxf(mx, redm[i]);
    float e0 = __expf(a0 - mx), e1 = __expf(a1 - mx);
    float s = e0 + e1;
#pragma unroll
    for (int off = 1; off < 64; off <<= 1) s += __shfl_xor(s, off);
    if (lane == 0) reds[wid] = s;
    __syncthreads();
    float tot = 0.f;
#pragma unroll
    for (int i = 0; i < 16; ++i) tot += reds[i];
    float inv = 1.0f / tot;
    out[b * 2048 + t] = e0 * inv;
    out[b * 2048 + 1024 + t] = e1 * inv;
}

// ---------------------------------------------------------------------------
extern "C" void kernel_launch(void* const* d_in, const int* in_sizes, int n_in,
                              void* d_out, int out_size, void* d_ws, size_t ws_size,
                              hipStream_t stream) {
    const float* query = (const float*)d_in[0];
    const float* value = (const float*)d_in[1];
    const int*   mask  = (const int*)d_in[2];
    const float* Wq    = (const float*)d_in[3];
    const float* bq    = (const float*)d_in[4];
    const float* Wv    = (const float*)d_in[5];
    const float* wv    = (const float*)d_in[6];

    char* ws = (char*)d_ws;
    f16*   BP    = (f16*)(ws + WS_BP);
    float* hq    = (float*)(ws + WS_HQ);
    float* lpart = (float*)(ws + WS_LP);
    float* out   = (float*)d_out;

    (void)hipMemsetAsync(hq, 0, BB * HH * sizeof(float), stream);
    pack_wv<<<(KK * HH) / 256, 256, 0, stream>>>(Wv, BP);
    hq_kernel<<<dim3(16, BB), 256, 0, stream>>>(query, Wq, bq, hq);
    fused_main<<<2048, 512, 49152, stream>>>(value, BP, hq, wv, lpart);
    softmax_kernel<<<BB, 1024, 0, stream>>>(lpart, mask, out);
}